// Round 4
// baseline (204.494 us; speedup 1.0000x reference)
//
#include <hip/hip_runtime.h>

// ---------------------------------------------------------------------------
// SelfAttention (dual cross-attention): B=4, S=1024, HID=1024, NH=16, DH=64
//   q1,k1,v1,q2,k2,v2 = x @ W*.T + b*   (bf16 MFMA, f32 accum)
//   out5 = attn(q1,k2,v2), out3 = attn(q2,k1,v1)
// ---------------------------------------------------------------------------

typedef __attribute__((ext_vector_type(8))) short bf16x8;
typedef __attribute__((ext_vector_type(4))) short bf16x4;
typedef __attribute__((ext_vector_type(4))) float f32x4;
typedef __attribute__((ext_vector_type(4))) short s16x4;

#define MFMA16(a, b, c) __builtin_amdgcn_mfma_f32_16x16x32_bf16(a, b, c, 0, 0, 0)

__device__ __forceinline__ f32x4 mfma16k(bf16x4 a, bf16x4 b, f32x4 c) {
#if __has_builtin(__builtin_amdgcn_mfma_f32_16x16x16bf16_1k)
  return __builtin_amdgcn_mfma_f32_16x16x16bf16_1k(a, b, c, 0, 0, 0);
#elif __has_builtin(__builtin_amdgcn_mfma_f32_16x16x16_bf16)
  return __builtin_amdgcn_mfma_f32_16x16x16_bf16(a, b, c, 0, 0, 0);
#else
  asm volatile("v_mfma_f32_16x16x16_bf16 %0, %1, %2, %0"
               : "+v"(c) : "v"(a), "v"(b));
  return c;
#endif
}

__device__ __forceinline__ unsigned short f2bf(float f) {
  unsigned u = __float_as_uint(f);
  u = (u + 0x7fffu + ((u >> 16) & 1u)) >> 16;  // RNE
  return (unsigned short)u;
}

__device__ __forceinline__ unsigned cvt_pk_bf16(float lo, float hi) {
  unsigned r;
  asm("v_cvt_pk_bf16_f32 %0, %1, %2" : "=v"(r) : "v"(lo), "v"(hi));
  return r;
}

__device__ __forceinline__ void gll16(const void* g, void* l) {
  __builtin_amdgcn_global_load_lds(
      (const __attribute__((address_space(1))) unsigned int*)g,
      (__attribute__((address_space(3))) unsigned int*)l, 16, 0, 0);
}

// ---------------------------------------------------------------------------
// Kernel 1: f32 -> bf16 conversion of x (4M) and the 6 weight matrices (6x1M)
// ---------------------------------------------------------------------------
__global__ __launch_bounds__(256) void convert_k(
    const float* __restrict__ x,
    const float* __restrict__ W0, const float* __restrict__ W1,
    const float* __restrict__ W2, const float* __restrict__ W3,
    const float* __restrict__ W4, const float* __restrict__ W5,
    short* __restrict__ xbf, short* __restrict__ wbf) {
  const int tid = blockIdx.x * 256 + threadIdx.x;
  const int e = tid << 2;
  const float* src;
  short* dst;
  int off;
  if (e < (4 << 20)) {
    src = x; dst = xbf; off = e;
  } else {
    const int j = e - (4 << 20);
    const int wsel = j >> 20;
    off = j & ((1 << 20) - 1);
    src = (wsel == 0) ? W0 : (wsel == 1) ? W1 : (wsel == 2) ? W2
        : (wsel == 3) ? W3 : (wsel == 4) ? W4 : W5;
    dst = wbf + ((size_t)wsel << 20);
  }
  const float4 v = *(const float4*)(src + off);
  s16x4 o;
  o.x = (short)f2bf(v.x);
  o.y = (short)f2bf(v.y);
  o.z = (short)f2bf(v.z);
  o.w = (short)f2bf(v.w);
  *(s16x4*)(dst + off) = o;
}

// ---------------------------------------------------------------------------
// Kernel 2: projection GEMM, 8-phase 256x256 template (T1+T2+T3+T4+T5).
//   C = xbf @ W^T + bias over [M=4096][N=6144], BK=64, 512 thr (8 waves 2Mx4N),
//   LDS 128 KiB = 2 K-tile buffers x (A 256x64 + B 256x64) bf16.
//   Per phase: 12 ds_read_b128 (chunk-XOR swizzled) || stage 0-4 gll16 ->
//   barrier -> 16 MFMA (setprio) -> barrier. vmcnt(4) at phases 4,8 only.
//   Staging targets each region the phase AFTER its last read (ledger in
//   commit msg); all ds/stage regions disjoint per phase.
//   Output written bf16 in attention layouts (Q natural, K d-chunk-swz,
//   V transposed 64x64 tiles s-chunk-swz).
// ---------------------------------------------------------------------------
#define STAGE_A(T, H)                                                     \
  {                                                                       \
    const int k0s = (T) << 6;                                             \
    _Pragma("unroll") for (int ii = 0; ii < 2; ++ii) {                    \
      const int slot = ((H) << 10) + (w << 7) + (ii << 6) + lane;         \
      const int rr = slot >> 3;                                           \
      const int gc = (slot & 7) ^ (rr & 7);                               \
      gll16(Ag + (size_t)(m0 + rr) * 1024 + k0s + (gc << 3),              \
            &As[(T) & 1][((H) << 13) + (w << 10) + (ii << 9)]);           \
    }                                                                     \
  }

#define STAGE_B(T, H)                                                     \
  {                                                                       \
    const int k0s = (T) << 6;                                             \
    _Pragma("unroll") for (int ii = 0; ii < 2; ++ii) {                    \
      const int slot = ((H) << 10) + (w << 7) + (ii << 6) + lane;         \
      const int rr = slot >> 3;                                           \
      const int gc = (slot & 7) ^ (rr & 7);                               \
      gll16(Bg + (size_t)(nbase + rr) * 1024 + k0s + (gc << 3),           \
            &Bs[(T) & 1][((H) << 13) + (w << 10) + (ii << 9)]);           \
    }                                                                     \
  }

#define DS_LOADS(MH, NH, TB)                                              \
  bf16x8 af[4][2], bfr[2][2];                                             \
  _Pragma("unroll") for (int mi = 0; mi < 4; ++mi)                        \
    _Pragma("unroll") for (int kk = 0; kk < 2; ++kk) {                    \
      const int rA = (MH) * 128 + wr * 64 + mi * 16 + lr;                 \
      af[mi][kk] = *(const bf16x8*)                                       \
          &As[TB][rA * 64 + ((((kk << 2) + g) ^ (rA & 7)) << 3)];         \
    }                                                                     \
  _Pragma("unroll") for (int ni = 0; ni < 2; ++ni)                        \
    _Pragma("unroll") for (int kk = 0; kk < 2; ++kk) {                    \
      const int rB = (NH) * 128 + wc * 32 + ni * 16 + lr;                 \
      bfr[ni][kk] = *(const bf16x8*)                                      \
          &Bs[TB][rB * 64 + ((((kk << 2) + g) ^ (rB & 7)) << 3)];         \
    }

#define MFMA_PHASE(MH, NH)                                                \
  __builtin_amdgcn_s_barrier();                                           \
  __builtin_amdgcn_s_setprio(1);                                          \
  _Pragma("unroll") for (int mi = 0; mi < 4; ++mi)                        \
    _Pragma("unroll") for (int ni = 0; ni < 2; ++ni)                      \
      _Pragma("unroll") for (int kk = 0; kk < 2; ++kk)                    \
        acc[MH][NH][mi][ni] =                                             \
            MFMA16(af[mi][kk], bfr[ni][kk], acc[MH][NH][mi][ni]);         \
  __builtin_amdgcn_s_setprio(0);                                          \
  __builtin_amdgcn_s_barrier();

__global__ __launch_bounds__(512, 2) void proj_gemm8(
    const short* __restrict__ Ag, const short* __restrict__ W,
    const float* __restrict__ bq, const float* __restrict__ bk,
    const float* __restrict__ bv, const float* __restrict__ bq2,
    const float* __restrict__ bk2, const float* __restrict__ bv2,
    short* __restrict__ qkv) {
  __shared__ __align__(16) short As[2][16384];
  __shared__ __align__(16) short Bs[2][16384];

  const int bid = blockIdx.x;             // 384
  const int xcd = bid & 7, i = bid >> 3;  // 48 blocks per XCD
  const int nb = xcd * 3 + (i >> 4);      // each XCD owns 3 n-panels (B in L2)
  const int mbv = i & 15;
  const int m0 = mbv << 8;
  const int p = nb >> 2;                  // projection 0..5 (uniform per block)
  const int nbase = (nb & 3) << 8;        // col base within projection

  const short* Bg = W + ((size_t)p << 20);
  const int t = threadIdx.x, lane = t & 63, w = t >> 6;
  const int g = lane >> 4, lr = lane & 15;
  const int wr = w >> 2, wc = w & 3;      // 2M x 4N waves; wave C = 128x64

  f32x4 acc[2][2][4][2] = {};

  // prologue: tile0 (all), tile1 h0s; drain to 4 so tile0 is in LDS
  STAGE_A(0, 0); STAGE_B(0, 0); STAGE_A(0, 1); STAGE_B(0, 1);
  STAGE_A(1, 0); STAGE_B(1, 0);
  asm volatile("s_waitcnt vmcnt(4)" ::: "memory");
  __builtin_amdgcn_s_barrier();

  for (int j = 0; j < 8; ++j) {  // 2 K-tiles (2j->buf0, 2j+1->buf1) per iter
    const bool u = j < 7;
    { // ph1: C[0:128,0:128] x tile 2j
      DS_LOADS(0, 0, 0);
      STAGE_A(2 * j + 1, 1); STAGE_B(2 * j + 1, 1);
      MFMA_PHASE(0, 0);
    }
    { // ph2: C[0:128,128:256]
      DS_LOADS(0, 1, 0);
      MFMA_PHASE(0, 1);
    }
    { // ph3: C[128:256,0:128]  (A-buf0-h0 free -> stage tile 2j+2 A h0)
      DS_LOADS(1, 0, 0);
      if (u) STAGE_A(2 * j + 2, 0);
      MFMA_PHASE(1, 0);
    }
    { // ph4 (B-buf0-h0 free); vmcnt(4) guarantees tile 2j+1 landed for ph5-8
      DS_LOADS(1, 1, 0);
      if (u) {
        STAGE_B(2 * j + 2, 0);
        asm volatile("s_waitcnt vmcnt(4)" ::: "memory");
      } else {
        asm volatile("s_waitcnt vmcnt(0)" ::: "memory");
      }
      MFMA_PHASE(1, 1);
    }
    { // ph5: tile 2j+1 (buf1); A/B-buf0-h1 free -> stage tile 2j+2 h1s
      DS_LOADS(0, 0, 1);
      if (u) { STAGE_A(2 * j + 2, 1); STAGE_B(2 * j + 2, 1); }
      MFMA_PHASE(0, 0);
    }
    { // ph6
      DS_LOADS(0, 1, 1);
      MFMA_PHASE(0, 1);
    }
    { // ph7 (A-buf1-h0 free)
      DS_LOADS(1, 0, 1);
      if (u) STAGE_A(2 * j + 3, 0);
      MFMA_PHASE(1, 0);
    }
    { // ph8 (B-buf1-h0 free); vmcnt(4) guarantees tile 2j+2 for next ph1-4
      DS_LOADS(1, 1, 1);
      if (u) {
        STAGE_B(2 * j + 3, 0);
        asm volatile("s_waitcnt vmcnt(4)" ::: "memory");
      }
      MFMA_PHASE(1, 1);
    }
  }

  // ---- epilogue: bias + bf16 pack into attention layouts ----
  const float* bias = (p == 0) ? bq : (p == 1) ? bk : (p == 2) ? bv
                    : (p == 3) ? bq2 : (p == 4) ? bk2 : bv2;
  const int ptype = (p == 0 || p == 3) ? 0 : (p == 1 || p == 4) ? 1 : 2;
  unsigned short* dst = (unsigned short*)qkv + ((size_t)p << 22);
#pragma unroll
  for (int nh = 0; nh < 2; ++nh) {
#pragma unroll
    for (int ni = 0; ni < 2; ++ni) {
      const int nn = nbase + nh * 128 + wc * 32 + ni * 16 + lr;
      const float bb = bias[nn];
      const int h = nn >> 6, d = nn & 63;
#pragma unroll
      for (int mh = 0; mh < 2; ++mh) {
#pragma unroll
        for (int mi = 0; mi < 4; ++mi) {
#pragma unroll
          for (int r = 0; r < 4; ++r) {
            const int m = m0 + mh * 128 + wr * 64 + mi * 16 + (g << 2) + r;
            const int b = m >> 10, s = m & 1023;
            const unsigned short val = f2bf(acc[mh][nh][mi][ni][r] + bb);
            size_t idx;
            if (ptype == 0) {
              idx = ((size_t)(((b << 4) + h) * 1024 + s) << 6) + d;
            } else if (ptype == 1) {
              const int d2 = (d & 7) | (((d >> 3) ^ (s & 7)) << 3);
              idx = ((size_t)(((b << 4) + h) * 1024 + s) << 6) + d2;
            } else {
              const int tt = s >> 6, s2 = s & 63;
              const int s3 = (s2 & 7) | (((s2 >> 3) ^ (d & 7)) << 3);
              idx = ((size_t)((((b << 4) + h) * 16 + tt) * 64 + d) << 6) + s3;
            }
            dst[idx] = val;
          }
        }
      }
    }
  }
}

// ---------------------------------------------------------------------------
// Kernel 3: flash attention, swapped-QK^T in-register-P form (unchanged).
// ---------------------------------------------------------------------------
__global__ __launch_bounds__(256) void attn_k(const short* __restrict__ qkv,
                                              float* __restrict__ out) {
  __shared__ __align__(16) short Ks[2][64 * 64];
  __shared__ __align__(16) short Vs[2][64 * 64];

  const int L = blockIdx.x;  // 2048 blocks
  const int xcd = L & 7, ss = L >> 3;
  const int qt = ss & 15, pg = ss >> 4;
  const int pp = xcd + (pg << 3);  // all 16 q-tiles of a head share an XCD
  const int hb = pp & 63, dir = pp >> 6;

  const short* Q = qkv + ((size_t)(dir ? 3 : 0) << 22) + ((size_t)hb << 16);
  const short* K = qkv + ((size_t)(dir ? 1 : 4) << 22) + ((size_t)hb << 16);
  const short* V = qkv + ((size_t)(dir ? 2 : 5) << 22) + ((size_t)hb << 16);
  float* O = out + ((size_t)dir << 22);

  const int t = threadIdx.x, lane = t & 63, w = t >> 6;
  const int g = lane >> 4, lr = lane & 15;

  const int qrow = (qt << 6) + (w << 4) + lr;
  bf16x8 qf[2];
  qf[0] = *(const bf16x8*)(Q + qrow * 64 + g * 8);
  qf[1] = *(const bf16x8*)(Q + qrow * 64 + 32 + g * 8);

  const bf16x4 ones4 = {0x3F80, 0x3F80, 0x3F80, 0x3F80};

  f32x4 oacc[4] = {};
  f32x4 lacc = {};
  float mrun = -3.0e38f;               // running max for q = lr (log2 units)
  const float CSC = 0.18033688f;       // (1/8) * log2(e)

  const int srow = (w << 4) + (lane >> 3);  // staging row 0..63
  const int scol = (lane & 7) << 3;

  auto stage = [&](int kt, int buf) {
#pragma unroll
    for (int i = 0; i < 2; ++i) {
      gll16(K + (size_t)((kt << 6) + srow + i * 8) * 64 + scol,
            &Ks[buf][(w << 10) + (i << 9)]);
      gll16(V + (size_t)(kt << 12) + (size_t)(srow + i * 8) * 64 + scol,
            &Vs[buf][(w << 10) + (i << 9)]);
    }
  };

  stage(0, 0);
  asm volatile("s_waitcnt vmcnt(0)" ::: "memory");
  __builtin_amdgcn_s_barrier();

  int cur = 0;
  for (int kt = 0; kt < 16; ++kt) {
    if (kt < 15) stage(kt + 1, cur ^ 1);

    // ---- S^T = K Q^T (swapped): lane gets P^T[k=kn*16+g*4+r][q=lr] ----
    f32x4 sc2[4] = {};
    __builtin_amdgcn_s_setprio(1);
#pragma unroll
    for (int dk = 0; dk < 2; ++dk) {
#pragma unroll
      for (int kn = 0; kn < 4; ++kn) {
        const int krow = kn * 16 + lr;
        const bf16x8 kf = *(const bf16x8*)
            &Ks[cur][krow * 64 +
                     ((((dk << 6) + (g << 4)) ^ ((krow & 7) << 4)) >> 1)];
        sc2[kn] = MFMA16(kf, qf[dk], sc2[kn]);
      }
    }
    __builtin_amdgcn_s_setprio(0);

    // ---- softmax (per-lane scalar state, defer-max) ----
    float tm = fmaxf(fmaxf(fmaxf(sc2[0][0], sc2[0][1]),
                           fmaxf(sc2[0][2], sc2[0][3])),
                     fmaxf(fmaxf(sc2[1][0], sc2[1][1]),
                           fmaxf(sc2[1][2], sc2[1][3])));
    tm = fmaxf(tm, fmaxf(fmaxf(fmaxf(sc2[2][0], sc2[2][1]),
                               fmaxf(sc2[2][2], sc2[2][3])),
                         fmaxf(fmaxf(sc2[3][0], sc2[3][1]),
                               fmaxf(sc2[3][2], sc2[3][3]))));
    const bool ok = __all(fmaf(tm, CSC, -mrun) <= 8.0f);
    if (!ok) {
      float t2 = fmaxf(tm, __shfl_xor(tm, 16));
      t2 = fmaxf(t2, __shfl_xor(t2, 32));
      const float mnew = fmaxf(mrun, t2 * CSC);
      const float scq = exp2f(mrun - mnew);  // scale for q = lr
      mrun = mnew;
#pragma unroll
      for (int r = 0; r < 4; ++r) {
        const float sr = __shfl(scq, (g << 2) + r);  // scale for q = g*4+r
        lacc[r] *= sr;
#pragma unroll
        for (int dn = 0; dn < 4; ++dn) oacc[dn][r] *= sr;
      }
    }

    bf16x4 pa[4];
#pragma unroll
    for (int kn = 0; kn < 4; ++kn) {
      const float p0 = exp2f(fmaf(sc2[kn][0], CSC, -mrun));
      const float p1 = exp2f(fmaf(sc2[kn][1], CSC, -mrun));
      const float p2 = exp2f(fmaf(sc2[kn][2], CSC, -mrun));
      const float p3 = exp2f(fmaf(sc2[kn][3], CSC, -mrun));
      union { unsigned u[2]; bf16x4 v; } pk;
      pk.u[0] = cvt_pk_bf16(p0, p1);
      pk.u[1] = cvt_pk_bf16(p2, p3);
      pa[kn] = pk.v;
    }

    // ---- O += P V ; l += P @ ones  (K=16 MFMAs, P straight from regs) ----
    __builtin_amdgcn_s_setprio(1);
#pragma unroll
    for (int kn = 0; kn < 4; ++kn) {
      lacc = mfma16k(pa[kn], ones4, lacc);
#pragma unroll
      for (int dn = 0; dn < 4; ++dn) {
        const int vrow = dn * 16 + lr;
        const int ch = (2 * kn + (g >> 1)) ^ (vrow & 7);  // 16B-chunk swizzle
        const bf16x4 vf = *(const bf16x4*)
            &Vs[cur][vrow * 64 + ch * 8 + ((g & 1) << 2)];
        oacc[dn] = mfma16k(pa[kn], vf, oacc[dn]);
      }
    }
    __builtin_amdgcn_s_setprio(0);

    asm volatile("s_waitcnt vmcnt(0)" ::: "memory");
    __builtin_amdgcn_s_barrier();
    cur ^= 1;
  }

  // ---- epilogue: out[b][q][h*64+d] = oacc / l ----
  const int b = hb >> 4, h = hb & 15;
  float rl[4];
#pragma unroll
  for (int r = 0; r < 4; ++r) rl[r] = 1.0f / lacc[r];
#pragma unroll
  for (int dn = 0; dn < 4; ++dn) {
#pragma unroll
    for (int r = 0; r < 4; ++r) {
      const int q = (qt << 6) + (w << 4) + (g << 2) + r;
      const int d = dn * 16 + lr;
      O[((size_t)(b * 1024 + q) << 10) + h * 64 + d] = oacc[dn][r] * rl[r];
    }
  }
}

// ---------------------------------------------------------------------------
extern "C" void kernel_launch(void* const* d_in, const int* in_sizes, int n_in,
                              void* d_out, int out_size, void* d_ws,
                              size_t ws_size, hipStream_t stream) {
  const float* x   = (const float*)d_in[0];
  const float* Wq  = (const float*)d_in[1];
  const float* bq  = (const float*)d_in[2];
  const float* Wk  = (const float*)d_in[3];
  const float* bk  = (const float*)d_in[4];
  const float* Wv  = (const float*)d_in[5];
  const float* bv  = (const float*)d_in[6];
  const float* Wq2 = (const float*)d_in[7];
  const float* bq2 = (const float*)d_in[8];
  const float* Wk2 = (const float*)d_in[9];
  const float* bk2 = (const float*)d_in[10];
  const float* Wv2 = (const float*)d_in[11];
  const float* bv2 = (const float*)d_in[12];

  char* ws = (char*)d_ws;
  short* xbf = (short*)ws;                      // 8 MB
  short* wbf = (short*)(ws + 8388608);          // 12 MB
  short* qkv = (short*)(ws + 20971520);         // 6 x 8 MB

  convert_k<<<10240, 256, 0, stream>>>(x, Wq, Wk, Wv, Wq2, Wk2, Wv2, xbf, wbf);
  proj_gemm8<<<384, 512, 0, stream>>>(xbf, wbf, bq, bk, bv, bq2, bk2,
                                      bv2, qkv);
  attn_k<<<2048, 256, 0, stream>>>(qkv, (float*)d_out);
}

// Round 5
// 197.981 us; speedup vs baseline: 1.0329x; 1.0329x over previous
//
#include <hip/hip_runtime.h>

// ---------------------------------------------------------------------------
// SelfAttention (dual cross-attention): B=4, S=1024, HID=1024, NH=16, DH=64
//   q1,k1,v1,q2,k2,v2 = x @ W*.T + b*   (bf16 MFMA, f32 accum)
//   out5 = attn(q1,k2,v2), out3 = attn(q2,k1,v1)
// ---------------------------------------------------------------------------

typedef __attribute__((ext_vector_type(8))) short bf16x8;
typedef __attribute__((ext_vector_type(4))) short bf16x4;
typedef __attribute__((ext_vector_type(4))) float f32x4;
typedef __attribute__((ext_vector_type(4))) short s16x4;

#define MFMA16(a, b, c) __builtin_amdgcn_mfma_f32_16x16x32_bf16(a, b, c, 0, 0, 0)

__device__ __forceinline__ f32x4 mfma16k(bf16x4 a, bf16x4 b, f32x4 c) {
#if __has_builtin(__builtin_amdgcn_mfma_f32_16x16x16bf16_1k)
  return __builtin_amdgcn_mfma_f32_16x16x16bf16_1k(a, b, c, 0, 0, 0);
#elif __has_builtin(__builtin_amdgcn_mfma_f32_16x16x16_bf16)
  return __builtin_amdgcn_mfma_f32_16x16x16_bf16(a, b, c, 0, 0, 0);
#else
  asm volatile("v_mfma_f32_16x16x16_bf16 %0, %1, %2, %0"
               : "+v"(c) : "v"(a), "v"(b));
  return c;
#endif
}

__device__ __forceinline__ unsigned short f2bf(float f) {
  unsigned u = __float_as_uint(f);
  u = (u + 0x7fffu + ((u >> 16) & 1u)) >> 16;  // RNE
  return (unsigned short)u;
}

__device__ __forceinline__ unsigned cvt_pk_bf16(float lo, float hi) {
  unsigned r;
  asm("v_cvt_pk_bf16_f32 %0, %1, %2" : "=v"(r) : "v"(lo), "v"(hi));
  return r;
}

__device__ __forceinline__ void gll16(const void* g, void* l) {
  __builtin_amdgcn_global_load_lds(
      (const __attribute__((address_space(1))) unsigned int*)g,
      (__attribute__((address_space(3))) unsigned int*)l, 16, 0, 0);
}

// ---------------------------------------------------------------------------
// Kernel 1: f32 -> bf16 conversion of x (4M) and the 6 weight matrices (6x1M)
// ---------------------------------------------------------------------------
__global__ __launch_bounds__(256) void convert_k(
    const float* __restrict__ x,
    const float* __restrict__ W0, const float* __restrict__ W1,
    const float* __restrict__ W2, const float* __restrict__ W3,
    const float* __restrict__ W4, const float* __restrict__ W5,
    short* __restrict__ xbf, short* __restrict__ wbf) {
  const int tid = blockIdx.x * 256 + threadIdx.x;
  const int e = tid << 2;
  const float* src;
  short* dst;
  int off;
  if (e < (4 << 20)) {
    src = x; dst = xbf; off = e;
  } else {
    const int j = e - (4 << 20);
    const int wsel = j >> 20;
    off = j & ((1 << 20) - 1);
    src = (wsel == 0) ? W0 : (wsel == 1) ? W1 : (wsel == 2) ? W2
        : (wsel == 3) ? W3 : (wsel == 4) ? W4 : W5;
    dst = wbf + ((size_t)wsel << 20);
  }
  const float4 v = *(const float4*)(src + off);
  s16x4 o;
  o.x = (short)f2bf(v.x);
  o.y = (short)f2bf(v.y);
  o.z = (short)f2bf(v.z);
  o.w = (short)f2bf(v.w);
  *(s16x4*)(dst + off) = o;
}

// ---------------------------------------------------------------------------
// Kernel 2: projection GEMM, 8-phase 256x256 template (T1..T5), snake order.
//   Quadrant order per K-tile: (0,0)->(0,1)->(1,1)->(1,0); A-frags reused
//   across ph1-2 / ph3-4, B-frags across ph2-3 -> 28 ds_read_b128/K-tile
//   (was 48). Stage ledger (iter j, tiles 2j->buf0, 2j+1->buf1):
//     ph1: B(2j+1,h0) A(2j+1,h1) | ph3: A(2j+2,h0) | ph4: B(2j+2,h1) +vmcnt(4)
//     ph5: B(2j+2,h0) A(2j+2,h1) | ph7: A(2j+3,h0) | ph8: B(2j+3,h1) +vmcnt(4)
//   Each region staged the phase after its last read; vmcnt(4) at ph4 drains
//   through ph1 (tile 2j+1 complete for ph5), at ph8 through ph5 (tile 2j+2
//   complete for next ph1). Prologue stages tile0 full + A(1,h0),B(1,h1),
//   drains to 4 -> identical steady-state hand-off.
// ---------------------------------------------------------------------------
#define STAGE_A(T, H)                                                     \
  {                                                                       \
    const int k0s = (T) << 6;                                             \
    _Pragma("unroll") for (int ii = 0; ii < 2; ++ii) {                    \
      const int slot = ((H) << 10) + (w << 7) + (ii << 6) + lane;         \
      const int rr = slot >> 3;                                           \
      const int gc = (slot & 7) ^ (rr & 7);                               \
      gll16(Ag + (size_t)(m0 + rr) * 1024 + k0s + (gc << 3),              \
            &As[(T) & 1][((H) << 13) + (w << 10) + (ii << 9)]);           \
    }                                                                     \
  }

#define STAGE_B(T, H)                                                     \
  {                                                                       \
    const int k0s = (T) << 6;                                             \
    _Pragma("unroll") for (int ii = 0; ii < 2; ++ii) {                    \
      const int slot = ((H) << 10) + (w << 7) + (ii << 6) + lane;         \
      const int rr = slot >> 3;                                           \
      const int gc = (slot & 7) ^ (rr & 7);                               \
      gll16(Bg + (size_t)(nbase + rr) * 1024 + k0s + (gc << 3),           \
            &Bs[(T) & 1][((H) << 13) + (w << 10) + (ii << 9)]);           \
    }                                                                     \
  }

#define LOAD_A(MH, TB)                                                    \
  _Pragma("unroll") for (int mi = 0; mi < 4; ++mi)                        \
    _Pragma("unroll") for (int kk = 0; kk < 2; ++kk) {                    \
      const int rA = (MH) * 128 + wr * 64 + mi * 16 + lr;                 \
      af[mi][kk] = *(const bf16x8*)                                       \
          &As[TB][rA * 64 + ((((kk << 2) + g) ^ (rA & 7)) << 3)];         \
    }

#define LOAD_B(NH, TB)                                                    \
  _Pragma("unroll") for (int ni = 0; ni < 2; ++ni)                        \
    _Pragma("unroll") for (int kk = 0; kk < 2; ++kk) {                    \
      const int rB = (NH) * 128 + wc * 32 + ni * 16 + lr;                 \
      bfr[ni][kk] = *(const bf16x8*)                                      \
          &Bs[TB][rB * 64 + ((((kk << 2) + g) ^ (rB & 7)) << 3)];         \
    }

#define MFMA_PHASE(MH, NH)                                                \
  __builtin_amdgcn_s_barrier();                                           \
  __builtin_amdgcn_s_setprio(1);                                          \
  _Pragma("unroll") for (int mi = 0; mi < 4; ++mi)                        \
    _Pragma("unroll") for (int ni = 0; ni < 2; ++ni)                      \
      _Pragma("unroll") for (int kk = 0; kk < 2; ++kk)                    \
        acc[MH][NH][mi][ni] =                                             \
            MFMA16(af[mi][kk], bfr[ni][kk], acc[MH][NH][mi][ni]);         \
  __builtin_amdgcn_s_setprio(0);                                          \
  __builtin_amdgcn_s_barrier();

__global__ __launch_bounds__(512, 2) void proj_gemm8(
    const short* __restrict__ Ag, const short* __restrict__ W,
    const float* __restrict__ bq, const float* __restrict__ bk,
    const float* __restrict__ bv, const float* __restrict__ bq2,
    const float* __restrict__ bk2, const float* __restrict__ bv2,
    short* __restrict__ qkv) {
  __shared__ __align__(16) short As[2][16384];
  __shared__ __align__(16) short Bs[2][16384];

  const int bid = blockIdx.x;             // 384
  const int xcd = bid & 7, i = bid >> 3;  // 48 blocks per XCD
  const int nb = xcd * 3 + (i >> 4);      // each XCD owns 3 n-panels (B in L2)
  const int mbv = i & 15;
  const int m0 = mbv << 8;
  const int p = nb >> 2;                  // projection 0..5 (uniform per block)
  const int nbase = (nb & 3) << 8;        // col base within projection

  const short* Bg = W + ((size_t)p << 20);
  const int t = threadIdx.x, lane = t & 63, w = t >> 6;
  const int g = lane >> 4, lr = lane & 15;
  const int wr = w >> 2, wc = w & 3;      // 2M x 4N waves; wave C = 128x64

  f32x4 acc[2][2][4][2] = {};
  bf16x8 af[4][2], bfr[2][2];

  // prologue: tile0 complete + A(1,h0),B(1,h1); drain to 4 (tile0 in LDS)
  STAGE_A(0, 0); STAGE_B(0, 1); STAGE_B(0, 0); STAGE_A(0, 1);
  STAGE_A(1, 0); STAGE_B(1, 1);
  asm volatile("s_waitcnt vmcnt(4)" ::: "memory");
  __builtin_amdgcn_s_barrier();

  for (int j = 0; j < 8; ++j) {  // 2 K-tiles (2j->buf0, 2j+1->buf1) per iter
    const bool u = j < 7;
    { // ph1 (0,0) buf0: 12 ds; stage tile2j+1 remainder
      LOAD_A(0, 0); LOAD_B(0, 0);
      STAGE_B(2 * j + 1, 0); STAGE_A(2 * j + 1, 1);
      MFMA_PHASE(0, 0);
    }
    { // ph2 (0,1): 4 ds (reuse af)
      LOAD_B(1, 0);
      MFMA_PHASE(0, 1);
    }
    { // ph3 (1,1): 8 ds (reuse bfr); A-buf0-h0 free -> stage
      LOAD_A(1, 0);
      if (u) STAGE_A(2 * j + 2, 0);
      MFMA_PHASE(1, 1);
    }
    { // ph4 (1,0): 4 ds; B-buf0-h1 free -> stage; vmcnt(4) = tile2j+1 landed
      LOAD_B(0, 0);
      if (u) {
        STAGE_B(2 * j + 2, 1);
        asm volatile("s_waitcnt vmcnt(4)" ::: "memory");
      } else {
        asm volatile("s_waitcnt vmcnt(0)" ::: "memory");
      }
      MFMA_PHASE(1, 0);
    }
    { // ph5 (0,0) buf1: 12 ds; B-buf0-h0 & A-buf0-h1 free -> stage
      LOAD_A(0, 1); LOAD_B(0, 1);
      if (u) { STAGE_B(2 * j + 2, 0); STAGE_A(2 * j + 2, 1); }
      MFMA_PHASE(0, 0);
    }
    { // ph6 (0,1): 4 ds
      LOAD_B(1, 1);
      MFMA_PHASE(0, 1);
    }
    { // ph7 (1,1): 8 ds; A-buf1-h0 free -> stage
      LOAD_A(1, 1);
      if (u) STAGE_A(2 * j + 3, 0);
      MFMA_PHASE(1, 1);
    }
    { // ph8 (1,0): 4 ds; B-buf1-h1 free -> stage; vmcnt(4) = tile2j+2 landed
      LOAD_B(0, 1);
      if (u) {
        STAGE_B(2 * j + 3, 1);
        asm volatile("s_waitcnt vmcnt(4)" ::: "memory");
      }
      MFMA_PHASE(1, 0);
    }
  }

  // ---- epilogue: bias + bf16 pack into attention layouts ----
  const float* bias = (p == 0) ? bq : (p == 1) ? bk : (p == 2) ? bv
                    : (p == 3) ? bq2 : (p == 4) ? bk2 : bv2;
  const int ptype = (p == 0 || p == 3) ? 0 : (p == 1 || p == 4) ? 1 : 2;
  unsigned short* dst = (unsigned short*)qkv + ((size_t)p << 22);
#pragma unroll
  for (int nh = 0; nh < 2; ++nh) {
#pragma unroll
    for (int ni = 0; ni < 2; ++ni) {
      const int nn = nbase + nh * 128 + wc * 32 + ni * 16 + lr;
      const float bb = bias[nn];
      const int h = nn >> 6, d = nn & 63;
#pragma unroll
      for (int mh = 0; mh < 2; ++mh) {
#pragma unroll
        for (int mi = 0; mi < 4; ++mi) {
#pragma unroll
          for (int r = 0; r < 4; ++r) {
            const int m = m0 + mh * 128 + wr * 64 + mi * 16 + (g << 2) + r;
            const int b = m >> 10, s = m & 1023;
            const unsigned short val = f2bf(acc[mh][nh][mi][ni][r] + bb);
            size_t idx;
            if (ptype == 0) {
              idx = ((size_t)(((b << 4) + h) * 1024 + s) << 6) + d;
            } else if (ptype == 1) {
              const int d2 = (d & 7) | (((d >> 3) ^ (s & 7)) << 3);
              idx = ((size_t)(((b << 4) + h) * 1024 + s) << 6) + d2;
            } else {
              const int tt = s >> 6, s2 = s & 63;
              const int s3 = (s2 & 7) | (((s2 >> 3) ^ (d & 7)) << 3);
              idx = ((size_t)((((b << 4) + h) * 16 + tt) * 64 + d) << 6) + s3;
            }
            dst[idx] = val;
          }
        }
      }
    }
  }
}

// ---------------------------------------------------------------------------
// Kernel 3: flash attention, swapped-QK^T in-register-P form (unchanged).
// ---------------------------------------------------------------------------
__global__ __launch_bounds__(256) void attn_k(const short* __restrict__ qkv,
                                              float* __restrict__ out) {
  __shared__ __align__(16) short Ks[2][64 * 64];
  __shared__ __align__(16) short Vs[2][64 * 64];

  const int L = blockIdx.x;  // 2048 blocks
  const int xcd = L & 7, ss = L >> 3;
  const int qt = ss & 15, pg = ss >> 4;
  const int pp = xcd + (pg << 3);  // all 16 q-tiles of a head share an XCD
  const int hb = pp & 63, dir = pp >> 6;

  const short* Q = qkv + ((size_t)(dir ? 3 : 0) << 22) + ((size_t)hb << 16);
  const short* K = qkv + ((size_t)(dir ? 1 : 4) << 22) + ((size_t)hb << 16);
  const short* V = qkv + ((size_t)(dir ? 2 : 5) << 22) + ((size_t)hb << 16);
  float* O = out + ((size_t)dir << 22);

  const int t = threadIdx.x, lane = t & 63, w = t >> 6;
  const int g = lane >> 4, lr = lane & 15;

  const int qrow = (qt << 6) + (w << 4) + lr;
  bf16x8 qf[2];
  qf[0] = *(const bf16x8*)(Q + qrow * 64 + g * 8);
  qf[1] = *(const bf16x8*)(Q + qrow * 64 + 32 + g * 8);

  const bf16x4 ones4 = {0x3F80, 0x3F80, 0x3F80, 0x3F80};

  f32x4 oacc[4] = {};
  f32x4 lacc = {};
  float mrun = -3.0e38f;               // running max for q = lr (log2 units)
  const float CSC = 0.18033688f;       // (1/8) * log2(e)

  const int srow = (w << 4) + (lane >> 3);  // staging row 0..63
  const int scol = (lane & 7) << 3;

  auto stage = [&](int kt, int buf) {
#pragma unroll
    for (int i = 0; i < 2; ++i) {
      gll16(K + (size_t)((kt << 6) + srow + i * 8) * 64 + scol,
            &Ks[buf][(w << 10) + (i << 9)]);
      gll16(V + (size_t)(kt << 12) + (size_t)(srow + i * 8) * 64 + scol,
            &Vs[buf][(w << 10) + (i << 9)]);
    }
  };

  stage(0, 0);
  asm volatile("s_waitcnt vmcnt(0)" ::: "memory");
  __builtin_amdgcn_s_barrier();

  int cur = 0;
  for (int kt = 0; kt < 16; ++kt) {
    if (kt < 15) stage(kt + 1, cur ^ 1);

    // ---- S^T = K Q^T (swapped): lane gets P^T[k=kn*16+g*4+r][q=lr] ----
    f32x4 sc2[4] = {};
    __builtin_amdgcn_s_setprio(1);
#pragma unroll
    for (int dk = 0; dk < 2; ++dk) {
#pragma unroll
      for (int kn = 0; kn < 4; ++kn) {
        const int krow = kn * 16 + lr;
        const bf16x8 kf = *(const bf16x8*)
            &Ks[cur][krow * 64 +
                     ((((dk << 6) + (g << 4)) ^ ((krow & 7) << 4)) >> 1)];
        sc2[kn] = MFMA16(kf, qf[dk], sc2[kn]);
      }
    }
    __builtin_amdgcn_s_setprio(0);

    // ---- softmax (per-lane scalar state, defer-max) ----
    float tm = fmaxf(fmaxf(fmaxf(sc2[0][0], sc2[0][1]),
                           fmaxf(sc2[0][2], sc2[0][3])),
                     fmaxf(fmaxf(sc2[1][0], sc2[1][1]),
                           fmaxf(sc2[1][2], sc2[1][3])));
    tm = fmaxf(tm, fmaxf(fmaxf(fmaxf(sc2[2][0], sc2[2][1]),
                               fmaxf(sc2[2][2], sc2[2][3])),
                         fmaxf(fmaxf(sc2[3][0], sc2[3][1]),
                               fmaxf(sc2[3][2], sc2[3][3]))));
    const bool ok = __all(fmaf(tm, CSC, -mrun) <= 8.0f);
    if (!ok) {
      float t2 = fmaxf(tm, __shfl_xor(tm, 16));
      t2 = fmaxf(t2, __shfl_xor(t2, 32));
      const float mnew = fmaxf(mrun, t2 * CSC);
      const float scq = exp2f(mrun - mnew);  // scale for q = lr
      mrun = mnew;
#pragma unroll
      for (int r = 0; r < 4; ++r) {
        const float sr = __shfl(scq, (g << 2) + r);  // scale for q = g*4+r
        lacc[r] *= sr;
#pragma unroll
        for (int dn = 0; dn < 4; ++dn) oacc[dn][r] *= sr;
      }
    }

    bf16x4 pa[4];
#pragma unroll
    for (int kn = 0; kn < 4; ++kn) {
      const float p0 = exp2f(fmaf(sc2[kn][0], CSC, -mrun));
      const float p1 = exp2f(fmaf(sc2[kn][1], CSC, -mrun));
      const float p2 = exp2f(fmaf(sc2[kn][2], CSC, -mrun));
      const float p3 = exp2f(fmaf(sc2[kn][3], CSC, -mrun));
      union { unsigned u[2]; bf16x4 v; } pk;
      pk.u[0] = cvt_pk_bf16(p0, p1);
      pk.u[1] = cvt_pk_bf16(p2, p3);
      pa[kn] = pk.v;
    }

    // ---- O += P V ; l += P @ ones  (K=16 MFMAs, P straight from regs) ----
    __builtin_amdgcn_s_setprio(1);
#pragma unroll
    for (int kn = 0; kn < 4; ++kn) {
      lacc = mfma16k(pa[kn], ones4, lacc);
#pragma unroll
      for (int dn = 0; dn < 4; ++dn) {
        const int vrow = dn * 16 + lr;
        const int ch = (2 * kn + (g >> 1)) ^ (vrow & 7);  // 16B-chunk swizzle
        const bf16x4 vf = *(const bf16x4*)
            &Vs[cur][vrow * 64 + ch * 8 + ((g & 1) << 2)];
        oacc[dn] = mfma16k(pa[kn], vf, oacc[dn]);
      }
    }
    __builtin_amdgcn_s_setprio(0);

    asm volatile("s_waitcnt vmcnt(0)" ::: "memory");
    __builtin_amdgcn_s_barrier();
    cur ^= 1;
  }

  // ---- epilogue: out[b][q][h*64+d] = oacc / l ----
  const int b = hb >> 4, h = hb & 15;
  float rl[4];
#pragma unroll
  for (int r = 0; r < 4; ++r) rl[r] = 1.0f / lacc[r];
#pragma unroll
  for (int dn = 0; dn < 4; ++dn) {
#pragma unroll
    for (int r = 0; r < 4; ++r) {
      const int q = (qt << 6) + (w << 4) + (g << 2) + r;
      const int d = dn * 16 + lr;
      O[((size_t)(b * 1024 + q) << 10) + h * 64 + d] = oacc[dn][r] * rl[r];
    }
  }
}

// ---------------------------------------------------------------------------
extern "C" void kernel_launch(void* const* d_in, const int* in_sizes, int n_in,
                              void* d_out, int out_size, void* d_ws,
                              size_t ws_size, hipStream_t stream) {
  const float* x   = (const float*)d_in[0];
  const float* Wq  = (const float*)d_in[1];
  const float* bq  = (const float*)d_in[2];
  const float* Wk  = (const float*)d_in[3];
  const float* bk  = (const float*)d_in[4];
  const float* Wv  = (const float*)d_in[5];
  const float* bv  = (const float*)d_in[6];
  const float* Wq2 = (const float*)d_in[7];
  const float* bq2 = (const float*)d_in[8];
  const float* Wk2 = (const float*)d_in[9];
  const float* bk2 = (const float*)d_in[10];
  const float* Wv2 = (const float*)d_in[11];
  const float* bv2 = (const float*)d_in[12];

  char* ws = (char*)d_ws;
  short* xbf = (short*)ws;                      // 8 MB
  short* wbf = (short*)(ws + 8388608);          // 12 MB
  short* qkv = (short*)(ws + 20971520);         // 6 x 8 MB

  convert_k<<<10240, 256, 0, stream>>>(x, Wq, Wk, Wv, Wq2, Wk2, Wv2, xbf, wbf);
  proj_gemm8<<<384, 512, 0, stream>>>(xbf, wbf, bq, bk, bv, bq2, bk2,
                                      bv2, qkv);
  attn_k<<<2048, 256, 0, stream>>>(qkv, (float*)d_out);
}

// Round 6
// 170.092 us; speedup vs baseline: 1.2022x; 1.1640x over previous
//
#include <hip/hip_runtime.h>

// ---------------------------------------------------------------------------
// SelfAttention (dual cross-attention): B=4, S=1024, HID=1024, NH=16, DH=64
//   q1,k1,v1,q2,k2,v2 = x @ W*.T + b*   (bf16 MFMA, f32 accum)
//   out5 = attn(q1,k2,v2), out3 = attn(q2,k1,v1)
// ---------------------------------------------------------------------------

typedef __attribute__((ext_vector_type(8))) short bf16x8;
typedef __attribute__((ext_vector_type(4))) short bf16x4;
typedef __attribute__((ext_vector_type(4))) float f32x4;
typedef __attribute__((ext_vector_type(4))) short s16x4;

#define MFMA16(a, b, c) __builtin_amdgcn_mfma_f32_16x16x32_bf16(a, b, c, 0, 0, 0)

__device__ __forceinline__ f32x4 mfma16k(bf16x4 a, bf16x4 b, f32x4 c) {
#if __has_builtin(__builtin_amdgcn_mfma_f32_16x16x16bf16_1k)
  return __builtin_amdgcn_mfma_f32_16x16x16bf16_1k(a, b, c, 0, 0, 0);
#elif __has_builtin(__builtin_amdgcn_mfma_f32_16x16x16_bf16)
  return __builtin_amdgcn_mfma_f32_16x16x16_bf16(a, b, c, 0, 0, 0);
#else
  asm volatile("v_mfma_f32_16x16x16_bf16 %0, %1, %2, %0"
               : "+v"(c) : "v"(a), "v"(b));
  return c;
#endif
}

__device__ __forceinline__ unsigned short f2bf(float f) {
  unsigned u = __float_as_uint(f);
  u = (u + 0x7fffu + ((u >> 16) & 1u)) >> 16;  // RNE
  return (unsigned short)u;
}

__device__ __forceinline__ unsigned cvt_pk_bf16(float lo, float hi) {
  unsigned r;
  asm("v_cvt_pk_bf16_f32 %0, %1, %2" : "=v"(r) : "v"(lo), "v"(hi));
  return r;
}

__device__ __forceinline__ void gll16(const void* g, void* l) {
  __builtin_amdgcn_global_load_lds(
      (const __attribute__((address_space(1))) unsigned int*)g,
      (__attribute__((address_space(3))) unsigned int*)l, 16, 0, 0);
}

// ---------------------------------------------------------------------------
// Kernel 1: f32 -> bf16 conversion of x (4M) and the 6 weight matrices (6x1M)
// ---------------------------------------------------------------------------
__global__ __launch_bounds__(256) void convert_k(
    const float* __restrict__ x,
    const float* __restrict__ W0, const float* __restrict__ W1,
    const float* __restrict__ W2, const float* __restrict__ W3,
    const float* __restrict__ W4, const float* __restrict__ W5,
    short* __restrict__ xbf, short* __restrict__ wbf) {
  const int tid = blockIdx.x * 256 + threadIdx.x;
  const int e = tid << 2;
  const float* src;
  short* dst;
  int off;
  if (e < (4 << 20)) {
    src = x; dst = xbf; off = e;
  } else {
    const int j = e - (4 << 20);
    const int wsel = j >> 20;
    off = j & ((1 << 20) - 1);
    src = (wsel == 0) ? W0 : (wsel == 1) ? W1 : (wsel == 2) ? W2
        : (wsel == 3) ? W3 : (wsel == 4) ? W4 : W5;
    dst = wbf + ((size_t)wsel << 20);
  }
  const float4 v = *(const float4*)(src + off);
  s16x4 o;
  o.x = (short)f2bf(v.x);
  o.y = (short)f2bf(v.y);
  o.z = (short)f2bf(v.z);
  o.w = (short)f2bf(v.w);
  *(s16x4*)(dst + off) = o;
}

// ---------------------------------------------------------------------------
// Kernel 2: projection GEMM, occupancy-pipelined 128x128, BK=32.
//   256 thr (4 waves, wave-tile 64x64), 3-buffer LDS ring (48 KB -> 3
//   blocks/CU via __launch_bounds__(256,3)): co-resident blocks hide barrier
//   drains + L3 fetch latency (m114 mechanism). Counted prefetch: tile T+2
//   staged during iter T, vmcnt(4) keeps one full tile in flight (never 0 in
//   steady state). Chunk-XOR swizzle on staging source + ds_read (rule #21).
//   Grid 1536 = 6 exact rounds; each XCD owns 6 B-panels (1.5 MB, L2-res).
// ---------------------------------------------------------------------------
__global__ __launch_bounds__(256, 3) void proj_gemm32(
    const short* __restrict__ Ag, const short* __restrict__ W,
    const float* __restrict__ bq, const float* __restrict__ bk,
    const float* __restrict__ bv, const float* __restrict__ bq2,
    const float* __restrict__ bk2, const float* __restrict__ bv2,
    short* __restrict__ qkv) {
  __shared__ __align__(16) short As[3][128 * 32];
  __shared__ __align__(16) short Bs[3][128 * 32];

  const int bid = blockIdx.x;             // 1536
  const int xcd = bid & 7, i = bid >> 3;  // 192 per XCD
  const int nb = xcd * 6 + (i >> 5);      // 48 B-panels; 6 per XCD
  const int mb = i & 31;
  const int p = nb >> 3;                  // projection 0..5
  const int n0 = (nb & 7) << 7, m0 = mb << 7;

  const short* Bg = W + ((size_t)p << 20);
  const int t = threadIdx.x, lane = t & 63, w = t >> 6;
  const int g = lane >> 4, lr = lane & 15;
  const int wm = ((w >> 1) << 6), wn = ((w & 1) << 6);

  f32x4 acc[4][4] = {};

  auto stage = [&](int kt, int buf) {
    const int k0 = kt << 5;
#pragma unroll
    for (int ld = 0; ld < 2; ++ld) {
      const int slot = ld * 256 + t;         // 0..511
      const int rr = slot >> 2;              // row 0..127
      const int gc = (slot & 3) ^ (rr & 3);  // inverse chunk swizzle (source)
      gll16(Ag + (size_t)(m0 + rr) * 1024 + k0 + (gc << 3),
            &As[buf][slot * 8]);
      gll16(Bg + (size_t)(n0 + rr) * 1024 + k0 + (gc << 3),
            &Bs[buf][slot * 8]);
    }
  };

  // prologue: tiles 0,1 in flight; wait tile0 (8 outstanding -> keep 4)
  stage(0, 0);
  stage(1, 1);
  asm volatile("s_waitcnt vmcnt(4)" ::: "memory");
  __builtin_amdgcn_s_barrier();

  int buf = 0;
  for (int T = 0; T < 32; ++T) {
    if (T <= 29) stage(T + 2, (T + 2) % 3);  // 2-tile-deep prefetch

    bf16x8 af[4], bfr[4];
#pragma unroll
    for (int mi = 0; mi < 4; ++mi) {
      const int rA = wm + mi * 16 + lr;
      af[mi] = *(const bf16x8*)&As[buf][rA * 32 + ((g ^ (rA & 3)) << 3)];
    }
#pragma unroll
    for (int nj = 0; nj < 4; ++nj) {
      const int rB = wn + nj * 16 + lr;
      bfr[nj] = *(const bf16x8*)&Bs[buf][rB * 32 + ((g ^ (rB & 3)) << 3)];
    }

    __builtin_amdgcn_s_setprio(1);
#pragma unroll
    for (int mi = 0; mi < 4; ++mi)
#pragma unroll
      for (int nj = 0; nj < 4; ++nj)
        acc[mi][nj] = MFMA16(af[mi], bfr[nj], acc[mi][nj]);
    __builtin_amdgcn_s_setprio(0);

    if (T <= 29) {
      asm volatile("s_waitcnt vmcnt(4)" ::: "memory");  // tile T+1 landed
    } else if (T == 30) {
      asm volatile("s_waitcnt vmcnt(0)" ::: "memory");  // tile 31 landed
    }
    __builtin_amdgcn_s_barrier();
    buf = (buf == 2) ? 0 : buf + 1;
  }

  // ---- epilogue: bias + bf16 pack into attention layouts ----
  const float* bias = (p == 0) ? bq : (p == 1) ? bk : (p == 2) ? bv
                    : (p == 3) ? bq2 : (p == 4) ? bk2 : bv2;
  const int ptype = (p == 0 || p == 3) ? 0 : (p == 1 || p == 4) ? 1 : 2;
  unsigned short* dst = (unsigned short*)qkv + ((size_t)p << 22);
#pragma unroll
  for (int nj = 0; nj < 4; ++nj) {
    const int n = n0 + wn + nj * 16 + lr;
    const float bb = bias[n];
    const int h = n >> 6, d = n & 63;
#pragma unroll
    for (int mi = 0; mi < 4; ++mi) {
#pragma unroll
      for (int r = 0; r < 4; ++r) {
        const int m = m0 + wm + mi * 16 + (g << 2) + r;
        const int b = m >> 10, s = m & 1023;
        const unsigned short val = f2bf(acc[mi][nj][r] + bb);
        size_t idx;
        if (ptype == 0) {
          idx = ((size_t)(((b << 4) + h) * 1024 + s) << 6) + d;
        } else if (ptype == 1) {
          const int d2 = (d & 7) | (((d >> 3) ^ (s & 7)) << 3);
          idx = ((size_t)(((b << 4) + h) * 1024 + s) << 6) + d2;
        } else {
          const int tt = s >> 6, s2 = s & 63;
          const int s3 = (s2 & 7) | (((s2 >> 3) ^ (d & 7)) << 3);
          idx = ((size_t)((((b << 4) + h) * 16 + tt) * 64 + d) << 6) + s3;
        }
        dst[idx] = val;
      }
    }
  }
}

// ---------------------------------------------------------------------------
// Kernel 3: flash attention, swapped-QK^T in-register-P form (unchanged).
// ---------------------------------------------------------------------------
__global__ __launch_bounds__(256) void attn_k(const short* __restrict__ qkv,
                                              float* __restrict__ out) {
  __shared__ __align__(16) short Ks[2][64 * 64];
  __shared__ __align__(16) short Vs[2][64 * 64];

  const int L = blockIdx.x;  // 2048 blocks
  const int xcd = L & 7, ss = L >> 3;
  const int qt = ss & 15, pg = ss >> 4;
  const int pp = xcd + (pg << 3);  // all 16 q-tiles of a head share an XCD
  const int hb = pp & 63, dir = pp >> 6;

  const short* Q = qkv + ((size_t)(dir ? 3 : 0) << 22) + ((size_t)hb << 16);
  const short* K = qkv + ((size_t)(dir ? 1 : 4) << 22) + ((size_t)hb << 16);
  const short* V = qkv + ((size_t)(dir ? 2 : 5) << 22) + ((size_t)hb << 16);
  float* O = out + ((size_t)dir << 22);

  const int t = threadIdx.x, lane = t & 63, w = t >> 6;
  const int g = lane >> 4, lr = lane & 15;

  const int qrow = (qt << 6) + (w << 4) + lr;
  bf16x8 qf[2];
  qf[0] = *(const bf16x8*)(Q + qrow * 64 + g * 8);
  qf[1] = *(const bf16x8*)(Q + qrow * 64 + 32 + g * 8);

  const bf16x4 ones4 = {0x3F80, 0x3F80, 0x3F80, 0x3F80};

  f32x4 oacc[4] = {};
  f32x4 lacc = {};
  float mrun = -3.0e38f;               // running max for q = lr (log2 units)
  const float CSC = 0.18033688f;       // (1/8) * log2(e)

  const int srow = (w << 4) + (lane >> 3);  // staging row 0..63
  const int scol = (lane & 7) << 3;

  auto stage = [&](int kt, int buf) {
#pragma unroll
    for (int i = 0; i < 2; ++i) {
      gll16(K + (size_t)((kt << 6) + srow + i * 8) * 64 + scol,
            &Ks[buf][(w << 10) + (i << 9)]);
      gll16(V + (size_t)(kt << 12) + (size_t)(srow + i * 8) * 64 + scol,
            &Vs[buf][(w << 10) + (i << 9)]);
    }
  };

  stage(0, 0);
  asm volatile("s_waitcnt vmcnt(0)" ::: "memory");
  __builtin_amdgcn_s_barrier();

  int cur = 0;
  for (int kt = 0; kt < 16; ++kt) {
    if (kt < 15) stage(kt + 1, cur ^ 1);

    // ---- S^T = K Q^T (swapped): lane gets P^T[k=kn*16+g*4+r][q=lr] ----
    f32x4 sc2[4] = {};
    __builtin_amdgcn_s_setprio(1);
#pragma unroll
    for (int dk = 0; dk < 2; ++dk) {
#pragma unroll
      for (int kn = 0; kn < 4; ++kn) {
        const int krow = kn * 16 + lr;
        const bf16x8 kf = *(const bf16x8*)
            &Ks[cur][krow * 64 +
                     ((((dk << 6) + (g << 4)) ^ ((krow & 7) << 4)) >> 1)];
        sc2[kn] = MFMA16(kf, qf[dk], sc2[kn]);
      }
    }
    __builtin_amdgcn_s_setprio(0);

    // ---- softmax (per-lane scalar state, defer-max) ----
    float tm = fmaxf(fmaxf(fmaxf(sc2[0][0], sc2[0][1]),
                           fmaxf(sc2[0][2], sc2[0][3])),
                     fmaxf(fmaxf(sc2[1][0], sc2[1][1]),
                           fmaxf(sc2[1][2], sc2[1][3])));
    tm = fmaxf(tm, fmaxf(fmaxf(fmaxf(sc2[2][0], sc2[2][1]),
                               fmaxf(sc2[2][2], sc2[2][3])),
                         fmaxf(fmaxf(sc2[3][0], sc2[3][1]),
                               fmaxf(sc2[3][2], sc2[3][3]))));
    const bool ok = __all(fmaf(tm, CSC, -mrun) <= 8.0f);
    if (!ok) {
      float t2 = fmaxf(tm, __shfl_xor(tm, 16));
      t2 = fmaxf(t2, __shfl_xor(t2, 32));
      const float mnew = fmaxf(mrun, t2 * CSC);
      const float scq = exp2f(mrun - mnew);  // scale for q = lr
      mrun = mnew;
#pragma unroll
      for (int r = 0; r < 4; ++r) {
        const float sr = __shfl(scq, (g << 2) + r);  // scale for q = g*4+r
        lacc[r] *= sr;
#pragma unroll
        for (int dn = 0; dn < 4; ++dn) oacc[dn][r] *= sr;
      }
    }

    bf16x4 pa[4];
#pragma unroll
    for (int kn = 0; kn < 4; ++kn) {
      const float p0 = exp2f(fmaf(sc2[kn][0], CSC, -mrun));
      const float p1 = exp2f(fmaf(sc2[kn][1], CSC, -mrun));
      const float p2 = exp2f(fmaf(sc2[kn][2], CSC, -mrun));
      const float p3 = exp2f(fmaf(sc2[kn][3], CSC, -mrun));
      union { unsigned u[2]; bf16x4 v; } pk;
      pk.u[0] = cvt_pk_bf16(p0, p1);
      pk.u[1] = cvt_pk_bf16(p2, p3);
      pa[kn] = pk.v;
    }

    // ---- O += P V ; l += P @ ones  (K=16 MFMAs, P straight from regs) ----
    __builtin_amdgcn_s_setprio(1);
#pragma unroll
    for (int kn = 0; kn < 4; ++kn) {
      lacc = mfma16k(pa[kn], ones4, lacc);
#pragma unroll
      for (int dn = 0; dn < 4; ++dn) {
        const int vrow = dn * 16 + lr;
        const int ch = (2 * kn + (g >> 1)) ^ (vrow & 7);  // 16B-chunk swizzle
        const bf16x4 vf = *(const bf16x4*)
            &Vs[cur][vrow * 64 + ch * 8 + ((g & 1) << 2)];
        oacc[dn] = mfma16k(pa[kn], vf, oacc[dn]);
      }
    }
    __builtin_amdgcn_s_setprio(0);

    asm volatile("s_waitcnt vmcnt(0)" ::: "memory");
    __builtin_amdgcn_s_barrier();
    cur ^= 1;
  }

  // ---- epilogue: out[b][q][h*64+d] = oacc / l ----
  const int b = hb >> 4, h = hb & 15;
  float rl[4];
#pragma unroll
  for (int r = 0; r < 4; ++r) rl[r] = 1.0f / lacc[r];
#pragma unroll
  for (int dn = 0; dn < 4; ++dn) {
#pragma unroll
    for (int r = 0; r < 4; ++r) {
      const int q = (qt << 6) + (w << 4) + (g << 2) + r;
      const int d = dn * 16 + lr;
      O[((size_t)(b * 1024 + q) << 10) + h * 64 + d] = oacc[dn][r] * rl[r];
    }
  }
}

// ---------------------------------------------------------------------------
extern "C" void kernel_launch(void* const* d_in, const int* in_sizes, int n_in,
                              void* d_out, int out_size, void* d_ws,
                              size_t ws_size, hipStream_t stream) {
  const float* x   = (const float*)d_in[0];
  const float* Wq  = (const float*)d_in[1];
  const float* bq  = (const float*)d_in[2];
  const float* Wk  = (const float*)d_in[3];
  const float* bk  = (const float*)d_in[4];
  const float* Wv  = (const float*)d_in[5];
  const float* bv  = (const float*)d_in[6];
  const float* Wq2 = (const float*)d_in[7];
  const float* bq2 = (const float*)d_in[8];
  const float* Wk2 = (const float*)d_in[9];
  const float* bk2 = (const float*)d_in[10];
  const float* Wv2 = (const float*)d_in[11];
  const float* bv2 = (const float*)d_in[12];

  char* ws = (char*)d_ws;
  short* xbf = (short*)ws;                      // 8 MB
  short* wbf = (short*)(ws + 8388608);          // 12 MB
  short* qkv = (short*)(ws + 20971520);         // 6 x 8 MB

  convert_k<<<10240, 256, 0, stream>>>(x, Wq, Wk, Wv, Wq2, Wk2, Wv2, xbf, wbf);
  proj_gemm32<<<1536, 256, 0, stream>>>(xbf, wbf, bq, bk, bv, bq2, bk2,
                                        bv2, qkv);
  attn_k<<<2048, 256, 0, stream>>>(qkv, (float*)d_out);
}

// Round 7
// 163.045 us; speedup vs baseline: 1.2542x; 1.0432x over previous
//
#include <hip/hip_runtime.h>

// ---------------------------------------------------------------------------
// SelfAttention (dual cross-attention): B=4, S=1024, HID=1024, NH=16, DH=64
//   q1,k1,v1,q2,k2,v2 = x @ W*.T + b*   (bf16 MFMA, f32 accum)
//   out5 = attn(q1,k2,v2), out3 = attn(q2,k1,v1)
// ---------------------------------------------------------------------------

typedef __attribute__((ext_vector_type(8))) short bf16x8;
typedef __attribute__((ext_vector_type(4))) short bf16x4;
typedef __attribute__((ext_vector_type(4))) float f32x4;
typedef __attribute__((ext_vector_type(4))) short s16x4;

#define MFMA16(a, b, c) __builtin_amdgcn_mfma_f32_16x16x32_bf16(a, b, c, 0, 0, 0)
#define BARRIER() asm volatile("s_barrier" ::: "memory")
#define VMCNT0() asm volatile("s_waitcnt vmcnt(0)" ::: "memory")

__device__ __forceinline__ f32x4 mfma16k(bf16x4 a, bf16x4 b, f32x4 c) {
#if __has_builtin(__builtin_amdgcn_mfma_f32_16x16x16bf16_1k)
  return __builtin_amdgcn_mfma_f32_16x16x16bf16_1k(a, b, c, 0, 0, 0);
#elif __has_builtin(__builtin_amdgcn_mfma_f32_16x16x16_bf16)
  return __builtin_amdgcn_mfma_f32_16x16x16_bf16(a, b, c, 0, 0, 0);
#else
  asm volatile("v_mfma_f32_16x16x16_bf16 %0, %1, %2, %0"
               : "+v"(c) : "v"(a), "v"(b));
  return c;
#endif
}

__device__ __forceinline__ unsigned short f2bf(float f) {
  unsigned u = __float_as_uint(f);
  u = (u + 0x7fffu + ((u >> 16) & 1u)) >> 16;  // RNE
  return (unsigned short)u;
}

__device__ __forceinline__ unsigned cvt_pk_bf16(float lo, float hi) {
  unsigned r;
  asm("v_cvt_pk_bf16_f32 %0, %1, %2" : "=v"(r) : "v"(lo), "v"(hi));
  return r;
}

__device__ __forceinline__ void gll16(const void* g, void* l) {
  __builtin_amdgcn_global_load_lds(
      (const __attribute__((address_space(1))) unsigned int*)g,
      (__attribute__((address_space(3))) unsigned int*)l, 16, 0, 0);
}

// ---------------------------------------------------------------------------
// Kernel 1: f32 -> bf16 conversion of x (4M) and the 6 weight matrices (6x1M)
// ---------------------------------------------------------------------------
__global__ __launch_bounds__(256) void convert_k(
    const float* __restrict__ x,
    const float* __restrict__ W0, const float* __restrict__ W1,
    const float* __restrict__ W2, const float* __restrict__ W3,
    const float* __restrict__ W4, const float* __restrict__ W5,
    short* __restrict__ xbf, short* __restrict__ wbf) {
  const int tid = blockIdx.x * 256 + threadIdx.x;
  const int e = tid << 2;
  const float* src;
  short* dst;
  int off;
  if (e < (4 << 20)) {
    src = x; dst = xbf; off = e;
  } else {
    const int j = e - (4 << 20);
    const int wsel = j >> 20;
    off = j & ((1 << 20) - 1);
    src = (wsel == 0) ? W0 : (wsel == 1) ? W1 : (wsel == 2) ? W2
        : (wsel == 3) ? W3 : (wsel == 4) ? W4 : W5;
    dst = wbf + ((size_t)wsel << 20);
  }
  const float4 v = *(const float4*)(src + off);
  s16x4 o;
  o.x = (short)f2bf(v.x);
  o.y = (short)f2bf(v.y);
  o.z = (short)f2bf(v.z);
  o.w = (short)f2bf(v.w);
  *(s16x4*)(dst + off) = o;
}

// ---------------------------------------------------------------------------
// Kernel 2: projection GEMM, 8-phase 256x192, BK=64, 512 thr (8 waves 2Mx4N,
// wave-tile 128x48). W treated as one [6144x1024] matrix (p resolved in
// epilogue per column). All barriers are compiler-fenced asm ("memory") so
// the phase schedule survives codegen (rounds 4/5 failure mode). Per K-tile:
// 4 phases (kk,mh) with B-frag reuse (22 ds_read_b128); next tile dribbled
// into the freed buffer across the other group's phases; one vmcnt(0) per
// K-tile, after the last phase's MFMA. Grid 512 = 2 exact occupancy rounds.
// ---------------------------------------------------------------------------
__global__ __launch_bounds__(512, 2) void proj_gemm192(
    const short* __restrict__ Ag, const short* __restrict__ Wall,
    const float* __restrict__ bq, const float* __restrict__ bk,
    const float* __restrict__ bv, const float* __restrict__ bq2,
    const float* __restrict__ bk2, const float* __restrict__ bv2,
    short* __restrict__ qkv) {
  __shared__ __align__(16) short As[2][16384];  // 256 x 64
  __shared__ __align__(16) short Bs[2][12288];  // 192 x 64

  const int bid = blockIdx.x;            // 512
  const int xcd = bid & 7, k = bid >> 3; // 64 per XCD
  const int ns = k & 3, mb = k >> 2;     // 4 n-panels/XCD (1.5MB L2-hot)
  const int nbase = (xcd * 4 + ns) * 192;
  const int m0 = mb << 8;

  const int t = threadIdx.x, lane = t & 63, w = t >> 6;
  const int g = lane >> 4, lr = lane & 15;
  const int wr = w >> 2, wc = w & 3;     // 2M x 4N waves; wave C = 128x48

  f32x4 acc[2][4][3] = {};

  // stage helpers: linear LDS dest, inverse-chunk-swizzled global source
  auto stage_ah = [&](int T, int H) {  // A half H: rows H*128..+127, 2 instr
#pragma unroll
    for (int ld = 0; ld < 2; ++ld) {
      const int slot = (H << 10) + (ld << 9) + t;
      const int rr = slot >> 3;
      const int gc = (slot & 7) ^ (rr & 7);
      gll16(Ag + (size_t)(m0 + rr) * 1024 + (T << 6) + (gc << 3),
            &As[T & 1][slot * 8]);
    }
  };
  auto stage_b = [&](int T) {  // B 192 rows, 3 instr
#pragma unroll
    for (int ld = 0; ld < 3; ++ld) {
      const int slot = (ld << 9) + t;
      const int rr = slot >> 3;
      const int gc = (slot & 7) ^ (rr & 7);
      gll16(Wall + (size_t)(nbase + rr) * 1024 + (T << 6) + (gc << 3),
            &Bs[T & 1][slot * 8]);
    }
  };

  // prologue: tile 0 -> buf0
  stage_ah(0, 0); stage_ah(0, 1); stage_b(0);
  VMCNT0();
  BARRIER();

#define LOAD_A(MH, KK, TB)                                                \
  _Pragma("unroll") for (int mi = 0; mi < 4; ++mi) {                      \
    const int rA = wr * 128 + (MH) * 64 + mi * 16 + lr;                   \
    af[mi] = *(const bf16x8*)                                             \
        &As[TB][rA * 64 + ((((KK) * 4 + g) ^ (rA & 7)) << 3)];            \
  }
#define LOAD_B(KK, TB)                                                    \
  _Pragma("unroll") for (int nj = 0; nj < 3; ++nj) {                      \
    const int rB = wc * 48 + nj * 16 + lr;                                \
    bf[nj] = *(const bf16x8*)                                             \
        &Bs[TB][rB * 64 + ((((KK) * 4 + g) ^ (rB & 7)) << 3)];            \
  }
#define MFMA_PH(MH)                                                       \
  __builtin_amdgcn_s_setprio(1);                                          \
  _Pragma("unroll") for (int mi = 0; mi < 4; ++mi)                        \
    _Pragma("unroll") for (int nj = 0; nj < 3; ++nj)                      \
      acc[MH][mi][nj] = MFMA16(af[mi], bf[nj], acc[MH][mi][nj]);          \
  __builtin_amdgcn_s_setprio(0);

  // one 4-phase group: compute buf C (tile TC), dribble tile TD (if DV)
  auto group = [&](int C, int TC, int TD, bool DV) {
    bf16x8 af[4], bf[3];
    { // ph_a (kk0, mh0) + dribble A-half0
      LOAD_A(0, 0, C); LOAD_B(0, C);
      if (DV) stage_ah(TD, 0);
      BARRIER();
      MFMA_PH(0);
      BARRIER();
    }
    { // ph_b (kk0, mh1) + dribble A-half1   (bf reused)
      LOAD_A(1, 0, C);
      if (DV) stage_ah(TD, 1);
      BARRIER();
      MFMA_PH(1);
      BARRIER();
    }
    { // ph_c (kk1, mh0) + dribble B
      LOAD_A(0, 1, C); LOAD_B(1, C);
      if (DV) stage_b(TD);
      BARRIER();
      MFMA_PH(0);
      BARRIER();
    }
    { // ph_d (kk1, mh1); certify dribbled tile after MFMA
      LOAD_A(1, 1, C);
      BARRIER();
      MFMA_PH(1);
      VMCNT0();
      BARRIER();
    }
  };

  for (int j = 0; j < 8; ++j) {
    group(0, 2 * j, 2 * j + 1, true);
    group(1, 2 * j + 1, 2 * j + 2, j < 7);
  }

#undef LOAD_A
#undef LOAD_B
#undef MFMA_PH

  // ---- epilogue: bias + bf16 pack into attention layouts (per-column p) ----
#pragma unroll
  for (int nj = 0; nj < 3; ++nj) {
    const int nn = nbase + wc * 48 + nj * 16 + lr;
    const int p = nn >> 10, nl = nn & 1023;
    const float* bp = (p == 0) ? bq : (p == 1) ? bk : (p == 2) ? bv
                    : (p == 3) ? bq2 : (p == 4) ? bk2 : bv2;
    const float bb = bp[nl];
    const int h = nl >> 6, d = nl & 63;
    const int pt = (p == 0 || p == 3) ? 0 : (p == 1 || p == 4) ? 1 : 2;
    unsigned short* dst = (unsigned short*)qkv + ((size_t)p << 22);
#pragma unroll
    for (int mh = 0; mh < 2; ++mh) {
#pragma unroll
      for (int mi = 0; mi < 4; ++mi) {
#pragma unroll
        for (int r = 0; r < 4; ++r) {
          const int m = m0 + wr * 128 + mh * 64 + mi * 16 + (g << 2) + r;
          const int b = m >> 10, s = m & 1023;
          const unsigned short val = f2bf(acc[mh][mi][nj][r] + bb);
          size_t idx;
          if (pt == 0) {
            idx = ((size_t)(((b << 4) + h) * 1024 + s) << 6) + d;
          } else if (pt == 1) {
            const int d2 = (d & 7) | (((d >> 3) ^ (s & 7)) << 3);
            idx = ((size_t)(((b << 4) + h) * 1024 + s) << 6) + d2;
          } else {
            const int tt = s >> 6, s2 = s & 63;
            const int s3 = (s2 & 7) | (((s2 >> 3) ^ (d & 7)) << 3);
            idx = ((size_t)((((b << 4) + h) * 16 + tt) * 64 + d) << 6) + s3;
          }
          dst[idx] = val;
        }
      }
    }
  }
}

// ---------------------------------------------------------------------------
// Kernel 3: flash attention, swapped-QK^T in-register-P form (unchanged).
// ---------------------------------------------------------------------------
__global__ __launch_bounds__(256) void attn_k(const short* __restrict__ qkv,
                                              float* __restrict__ out) {
  __shared__ __align__(16) short Ks[2][64 * 64];
  __shared__ __align__(16) short Vs[2][64 * 64];

  const int L = blockIdx.x;  // 2048 blocks
  const int xcd = L & 7, ss = L >> 3;
  const int qt = ss & 15, pg = ss >> 4;
  const int pp = xcd + (pg << 3);  // all 16 q-tiles of a head share an XCD
  const int hb = pp & 63, dir = pp >> 6;

  const short* Q = qkv + ((size_t)(dir ? 3 : 0) << 22) + ((size_t)hb << 16);
  const short* K = qkv + ((size_t)(dir ? 1 : 4) << 22) + ((size_t)hb << 16);
  const short* V = qkv + ((size_t)(dir ? 2 : 5) << 22) + ((size_t)hb << 16);
  float* O = out + ((size_t)dir << 22);

  const int t = threadIdx.x, lane = t & 63, w = t >> 6;
  const int g = lane >> 4, lr = lane & 15;

  const int qrow = (qt << 6) + (w << 4) + lr;
  bf16x8 qf[2];
  qf[0] = *(const bf16x8*)(Q + qrow * 64 + g * 8);
  qf[1] = *(const bf16x8*)(Q + qrow * 64 + 32 + g * 8);

  const bf16x4 ones4 = {0x3F80, 0x3F80, 0x3F80, 0x3F80};

  f32x4 oacc[4] = {};
  f32x4 lacc = {};
  float mrun = -3.0e38f;               // running max for q = lr (log2 units)
  const float CSC = 0.18033688f;       // (1/8) * log2(e)

  const int srow = (w << 4) + (lane >> 3);  // staging row 0..63
  const int scol = (lane & 7) << 3;

  auto stage = [&](int kt, int buf) {
#pragma unroll
    for (int i = 0; i < 2; ++i) {
      gll16(K + (size_t)((kt << 6) + srow + i * 8) * 64 + scol,
            &Ks[buf][(w << 10) + (i << 9)]);
      gll16(V + (size_t)(kt << 12) + (size_t)(srow + i * 8) * 64 + scol,
            &Vs[buf][(w << 10) + (i << 9)]);
    }
  };

  stage(0, 0);
  VMCNT0();
  BARRIER();

  int cur = 0;
  for (int kt = 0; kt < 16; ++kt) {
    if (kt < 15) stage(kt + 1, cur ^ 1);

    // ---- S^T = K Q^T (swapped): lane gets P^T[k=kn*16+g*4+r][q=lr] ----
    f32x4 sc2[4] = {};
    __builtin_amdgcn_s_setprio(1);
#pragma unroll
    for (int dk = 0; dk < 2; ++dk) {
#pragma unroll
      for (int kn = 0; kn < 4; ++kn) {
        const int krow = kn * 16 + lr;
        const bf16x8 kf = *(const bf16x8*)
            &Ks[cur][krow * 64 +
                     ((((dk << 6) + (g << 4)) ^ ((krow & 7) << 4)) >> 1)];
        sc2[kn] = MFMA16(kf, qf[dk], sc2[kn]);
      }
    }
    __builtin_amdgcn_s_setprio(0);

    // ---- softmax (per-lane scalar state, defer-max) ----
    float tm = fmaxf(fmaxf(fmaxf(sc2[0][0], sc2[0][1]),
                           fmaxf(sc2[0][2], sc2[0][3])),
                     fmaxf(fmaxf(sc2[1][0], sc2[1][1]),
                           fmaxf(sc2[1][2], sc2[1][3])));
    tm = fmaxf(tm, fmaxf(fmaxf(fmaxf(sc2[2][0], sc2[2][1]),
                               fmaxf(sc2[2][2], sc2[2][3])),
                         fmaxf(fmaxf(sc2[3][0], sc2[3][1]),
                               fmaxf(sc2[3][2], sc2[3][3]))));
    const bool ok = __all(fmaf(tm, CSC, -mrun) <= 8.0f);
    if (!ok) {
      float t2 = fmaxf(tm, __shfl_xor(tm, 16));
      t2 = fmaxf(t2, __shfl_xor(t2, 32));
      const float mnew = fmaxf(mrun, t2 * CSC);
      const float scq = exp2f(mrun - mnew);  // scale for q = lr
      mrun = mnew;
#pragma unroll
      for (int r = 0; r < 4; ++r) {
        const float sr = __shfl(scq, (g << 2) + r);  // scale for q = g*4+r
        lacc[r] *= sr;
#pragma unroll
        for (int dn = 0; dn < 4; ++dn) oacc[dn][r] *= sr;
      }
    }

    bf16x4 pa[4];
#pragma unroll
    for (int kn = 0; kn < 4; ++kn) {
      const float p0 = exp2f(fmaf(sc2[kn][0], CSC, -mrun));
      const float p1 = exp2f(fmaf(sc2[kn][1], CSC, -mrun));
      const float p2 = exp2f(fmaf(sc2[kn][2], CSC, -mrun));
      const float p3 = exp2f(fmaf(sc2[kn][3], CSC, -mrun));
      union { unsigned u[2]; bf16x4 v; } pk;
      pk.u[0] = cvt_pk_bf16(p0, p1);
      pk.u[1] = cvt_pk_bf16(p2, p3);
      pa[kn] = pk.v;
    }

    // ---- O += P V ; l += P @ ones  (K=16 MFMAs, P straight from regs) ----
    __builtin_amdgcn_s_setprio(1);
#pragma unroll
    for (int kn = 0; kn < 4; ++kn) {
      lacc = mfma16k(pa[kn], ones4, lacc);
#pragma unroll
      for (int dn = 0; dn < 4; ++dn) {
        const int vrow = dn * 16 + lr;
        const int ch = (2 * kn + (g >> 1)) ^ (vrow & 7);  // 16B-chunk swizzle
        const bf16x4 vf = *(const bf16x4*)
            &Vs[cur][vrow * 64 + ch * 8 + ((g & 1) << 2)];
        oacc[dn] = mfma16k(pa[kn], vf, oacc[dn]);
      }
    }
    __builtin_amdgcn_s_setprio(0);

    VMCNT0();
    BARRIER();
    cur ^= 1;
  }

  // ---- epilogue: out[b][q][h*64+d] = oacc / l ----
  const int b = hb >> 4, h = hb & 15;
  float rl[4];
#pragma unroll
  for (int r = 0; r < 4; ++r) rl[r] = 1.0f / lacc[r];
#pragma unroll
  for (int dn = 0; dn < 4; ++dn) {
#pragma unroll
    for (int r = 0; r < 4; ++r) {
      const int q = (qt << 6) + (w << 4) + (g << 2) + r;
      const int d = dn * 16 + lr;
      O[((size_t)(b * 1024 + q) << 10) + h * 64 + d] = oacc[dn][r] * rl[r];
    }
  }
}

// ---------------------------------------------------------------------------
extern "C" void kernel_launch(void* const* d_in, const int* in_sizes, int n_in,
                              void* d_out, int out_size, void* d_ws,
                              size_t ws_size, hipStream_t stream) {
  const float* x   = (const float*)d_in[0];
  const float* Wq  = (const float*)d_in[1];
  const float* bq  = (const float*)d_in[2];
  const float* Wk  = (const float*)d_in[3];
  const float* bk  = (const float*)d_in[4];
  const float* Wv  = (const float*)d_in[5];
  const float* bv  = (const float*)d_in[6];
  const float* Wq2 = (const float*)d_in[7];
  const float* bq2 = (const float*)d_in[8];
  const float* Wk2 = (const float*)d_in[9];
  const float* bk2 = (const float*)d_in[10];
  const float* Wv2 = (const float*)d_in[11];
  const float* bv2 = (const float*)d_in[12];

  char* ws = (char*)d_ws;
  short* xbf = (short*)ws;                      // 8 MB
  short* wbf = (short*)(ws + 8388608);          // 12 MB
  short* qkv = (short*)(ws + 20971520);         // 6 x 8 MB

  convert_k<<<10240, 256, 0, stream>>>(x, Wq, Wk, Wv, Wq2, Wk2, Wv2, xbf, wbf);
  proj_gemm192<<<512, 512, 0, stream>>>(xbf, wbf, bq, bk, bv, bq2, bk2,
                                        bv2, qkv);
  attn_k<<<2048, 256, 0, stream>>>(qkv, (float*)d_out);
}